// Round 1
// baseline (536.856 us; speedup 1.0000x reference)
//
#include <hip/hip_runtime.h>
#include <stdint.h>

#define S 1024
#define D 64
#define TQ 16
#define KT 256
#define NKT 4
#define NEG (-1e15f)
#define SCALE 0.125f

#define WB_STRIDE 1048   // bf16 elems; 2096 B row, 16B-aligned, banks uniform
#define KB_STRIDE 72     // bf16 elems; 144 B row
#define VT_STRIDE 264    // bf16 elems; 528 B row
#define QS_STRIDE 72

typedef __bf16 bf16x8 __attribute__((ext_vector_type(8)));
typedef float f32x4 __attribute__((ext_vector_type(4)));

__device__ __forceinline__ unsigned short f2b(float f) {
  union { float f; uint32_t u; } c; c.f = f;
  uint32_t u = c.u;
  return (unsigned short)((u + 0x7fffu + ((u >> 16) & 1u)) >> 16);  // RNE
}
__device__ __forceinline__ float b2f(uint32_t u) {
  union { uint32_t u; float f; } c; c.u = u << 16;
  return c.f;
}

__global__ __launch_bounds__(512, 4) void attn_kernel(
    const float* __restrict__ Qg, const float* __restrict__ Kg,
    const float* __restrict__ Vg, const int* __restrict__ PADg,
    float* __restrict__ OCTX, float* __restrict__ OW)
{
  // wb: raw scores then weights (bf16). ub: K-tile (QK) / V^T-tile (PV) / partial buf.
  __shared__ __align__(16) unsigned short wb[TQ * WB_STRIDE];   // 33536 B
  __shared__ __align__(16) unsigned short ub[KT * KB_STRIDE];   // 36864 B
  __shared__ __align__(16) unsigned short qs[TQ * QS_STRIDE];   //  2304 B
  __shared__ __align__(16) float pbias[S];                      //  4096 B

  const int t  = threadIdx.x;
  const int w  = t >> 6;        // wave 0..7
  const int l  = t & 63;        // lane
  const int la = l & 15;
  const int lb = l >> 4;        // quad
  const int blk = blockIdx.x;
  const int bh  = blk >> 6;     // 64 consecutive blocks share one head (L2 reuse)
  const int qt  = blk & 63;
  const int qr0 = qt << 4;

  const size_t head = (size_t)bh * S * D;

  // ---- Phase 0: stage Q tile (bf16) + pad bias ----
  if (t < 256) {
    const int r = t >> 4, c4 = (t & 15) << 2;
    const float4 qv = *(const float4*)(Qg + head + (size_t)(qr0 + r) * D + c4);
    ushort4 o; o.x = f2b(qv.x); o.y = f2b(qv.y); o.z = f2b(qv.z); o.w = f2b(qv.w);
    *(ushort4*)&qs[r * QS_STRIDE + c4] = o;
  }
  {
    const int* pp = PADg + (size_t)(bh >> 4) * S;   // b = bh / H
    for (int j = t; j < S; j += 512) pbias[j] = pp[j] ? NEG : 0.0f;
  }
  __syncthreads();

  // Persistent Q A-frags: A[m=la][k=lb*8+j], k-halves of D=64
  const bf16x8 aq0 = *(const bf16x8*)&qs[la * QS_STRIDE +  0 + (lb << 3)];
  const bf16x8 aq1 = *(const bf16x8*)&qs[la * QS_STRIDE + 32 + (lb << 3)];

  // ---- Phase 1: QK^T -> raw bf16 scores in wb ----
  for (int kt = 0; kt < NKT; ++kt) {
    const float* kp = Kg + head + (size_t)(kt * KT) * D;
#pragma unroll
    for (int i = 0; i < 8; ++i) {             // stage 256x64 fp32 -> bf16 LDS
      int idx = i * 512 + t;
      int row = idx >> 4, c4 = (idx & 15) << 2;
      float4 kv = *(const float4*)(kp + (size_t)row * D + c4);
      ushort4 o; o.x = f2b(kv.x); o.y = f2b(kv.y); o.z = f2b(kv.z); o.w = f2b(kv.w);
      *(ushort4*)&ub[row * KB_STRIDE + c4] = o;
    }
    __syncthreads();
#pragma unroll
    for (int sj = 0; sj < 2; ++sj) {          // wave owns 32 keys -> 2 subtiles of 16
      const int j0 = (w << 5) + (sj << 4);
      f32x4 acc = {0.f, 0.f, 0.f, 0.f};
      bf16x8 b0 = *(const bf16x8*)&ub[(j0 + la) * KB_STRIDE +  0 + (lb << 3)];
      acc = __builtin_amdgcn_mfma_f32_16x16x32_bf16(aq0, b0, acc, 0, 0, 0);
      bf16x8 b1 = *(const bf16x8*)&ub[(j0 + la) * KB_STRIDE + 32 + (lb << 3)];
      acc = __builtin_amdgcn_mfma_f32_16x16x32_bf16(aq1, b1, acc, 0, 0, 0);
#pragma unroll
      for (int i = 0; i < 4; ++i)             // D: row=(lb*4+i)=q, col=la=key
        wb[((lb << 2) + i) * WB_STRIDE + kt * KT + j0 + la] = f2b(acc[i]);
    }
    __syncthreads();
  }

  // ---- Phase 2: fp32 softmax (2 rows per wave), in-place wb + global weights ----
#pragma unroll
  for (int rr = 0; rr < 2; ++rr) {
    const int r  = (w << 1) + rr;
    const int qr = qr0 + r;
    float lg[16];
    float m = -3.0e38f;
#pragma unroll
    for (int ii = 0; ii < 8; ++ii) {
      const int j = (l << 1) + (ii << 7);
      uint32_t pr = *(const uint32_t*)&wb[r * WB_STRIDE + j];
      float2 pb = *(const float2*)&pbias[j];
      float l0 = b2f(pr & 0xffffu) * SCALE + pb.x + ((j     > qr) ? NEG : 0.0f);
      float l1 = b2f(pr >> 16)     * SCALE + pb.y + ((j + 1 > qr) ? NEG : 0.0f);
      lg[2 * ii] = l0; lg[2 * ii + 1] = l1;
      m = fmaxf(m, fmaxf(l0, l1));
    }
#pragma unroll
    for (int off = 32; off > 0; off >>= 1) m = fmaxf(m, __shfl_xor(m, off, 64));
    float sum = 0.f;
#pragma unroll
    for (int x = 0; x < 16; ++x) { lg[x] = __expf(lg[x] - m); sum += lg[x]; }
#pragma unroll
    for (int off = 32; off > 0; off >>= 1) sum += __shfl_xor(sum, off, 64);
    const float inv = 1.0f / sum;
    float* orow = OW + (size_t)(bh * S + qr) * S;
#pragma unroll
    for (int ii = 0; ii < 8; ++ii) {
      const int j = (l << 1) + (ii << 7);
      float w0 = lg[2 * ii] * inv, w1 = lg[2 * ii + 1] * inv;
      *(uint32_t*)&wb[r * WB_STRIDE + j] = ((uint32_t)f2b(w1) << 16) | (uint32_t)f2b(w0);
      *(float2*)&orow[j] = make_float2(w0, w1);
    }
  }
  __syncthreads();

  // ---- Phase 3: PV. wave -> (d-tile = (w&3)*16, j-half = w>>2) ----
  const int jh = w >> 2;
  const int d0 = (w & 3) << 4;
  f32x4 cacc = {0.f, 0.f, 0.f, 0.f};
  for (int kt = 0; kt < NKT; ++kt) {
    const float* vp = Vg + head + (size_t)(kt * KT) * D;
    {   // stage V^T tile: vt[d][j] bf16, packed pairs along j
      const int jp = t & 127;
      const int db = (t >> 7) << 4;
      const float* vr0 = vp + (size_t)(jp << 1) * D + db;
      float a0[16], a1[16];
#pragma unroll
      for (int c = 0; c < 4; ++c) {
        *(float4*)&a0[c << 2] = *(const float4*)(vr0 + (c << 2));
        *(float4*)&a1[c << 2] = *(const float4*)(vr0 + D + (c << 2));
      }
#pragma unroll
      for (int dd = 0; dd < 16; ++dd) {
        uint32_t pk = ((uint32_t)f2b(a1[dd]) << 16) | (uint32_t)f2b(a0[dd]);
        *(uint32_t*)&ub[(db + dd) * VT_STRIDE + (jp << 1)] = pk;
      }
    }
    __syncthreads();
#pragma unroll
    for (int ks = 0; ks < 4; ++ks) {
      const int jt = jh * 128 + ks * 32;
      bf16x8 af = *(const bf16x8*)&wb[la * WB_STRIDE + kt * KT + jt + (lb << 3)];
      bf16x8 bf = *(const bf16x8*)&ub[(d0 + la) * VT_STRIDE + jt + (lb << 3)];
      cacc = __builtin_amdgcn_mfma_f32_16x16x32_bf16(af, bf, cacc, 0, 0, 0);
    }
    __syncthreads();
  }

  // ---- Phase 4: reduce the two j-halves, store context ----
  float* pbuf = (float*)ub;                    // 4*16*20 fp32, padded
  if (w >= 4) {
#pragma unroll
    for (int i = 0; i < 4; ++i)
      pbuf[(w - 4) * 320 + ((lb << 2) + i) * 20 + la] = cacc[i];
  }
  __syncthreads();
  if (w < 4) {
#pragma unroll
    for (int i = 0; i < 4; ++i) {
      const int qrow = (lb << 2) + i;
      OCTX[((size_t)(bh * S) + qr0 + qrow) * D + d0 + la] =
          cacc[i] + pbuf[w * 320 + qrow * 20 + la];
    }
  }
}

extern "C" void kernel_launch(void* const* d_in, const int* in_sizes, int n_in,
                              void* d_out, int out_size, void* d_ws, size_t ws_size,
                              hipStream_t stream) {
  const float* q   = (const float*)d_in[0];
  const float* k   = (const float*)d_in[1];
  const float* v   = (const float*)d_in[2];
  const int*   pad = (const int*)d_in[3];
  // d_in[4] (look_ahead_mask) is reproduced analytically from indices.
  float* ctx = (float*)d_out;
  float* wout = (float*)d_out + (size_t)4 * 16 * S * D;   // weights after context
  attn_kernel<<<dim3(64 * 64), dim3(512), 0, stream>>>(q, k, v, pad, ctx, wout);
}

// Round 2
// 413.945 us; speedup vs baseline: 1.2969x; 1.2969x over previous
//
#include <hip/hip_runtime.h>
#include <stdint.h>

#define S 1024
#define D 64
#define TQ 16
#define KT 256
#define NKT 4
#define NEG (-1e15f)
#define SCALE 0.125f

#define WB_STRIDE 1048   // bf16 elems; 2096 B row, 16B-aligned; af-read 2-way free
#define KB_STRIDE 72     // bf16 elems; 144 B row (16B mult); staging/read ~min cycles
#define VT_STRIDE 264    // bf16 elems; 528 B row (16B mult)
#define QS_STRIDE 72

typedef __bf16 bf16x8 __attribute__((ext_vector_type(8)));
typedef float f32x4 __attribute__((ext_vector_type(4)));
typedef unsigned short ushort_t;

__device__ __forceinline__ unsigned short f2b(float f) {
  union { float f; uint32_t u; } c; c.f = f;
  uint32_t u = c.u;
  return (unsigned short)((u + 0x7fffu + ((u >> 16) & 1u)) >> 16);  // RNE
}
__device__ __forceinline__ float b2f(uint32_t u) {
  union { uint32_t u; float f; } c; c.u = u << 16;
  return c.f;
}

// ---- prep 1: K fp32 -> bf16, straight layout [bh][j][d] ----
__global__ __launch_bounds__(256) void prep_k_kernel(
    const float* __restrict__ Kg, ushort_t* __restrict__ Kb)
{
  const size_t idx = ((size_t)blockIdx.x * 256 + threadIdx.x) * 8;
  float4 a = *(const float4*)(Kg + idx);
  float4 b = *(const float4*)(Kg + idx + 4);
  ushort_t tmp[8];
  tmp[0]=f2b(a.x); tmp[1]=f2b(a.y); tmp[2]=f2b(a.z); tmp[3]=f2b(a.w);
  tmp[4]=f2b(b.x); tmp[5]=f2b(b.y); tmp[6]=f2b(b.z); tmp[7]=f2b(b.w);
  *(uint4*)(Kb + idx) = *(const uint4*)tmp;
}

// ---- prep 2: V fp32 [bh][j][d] -> bf16 transposed Vt [bh][d][j] ----
__global__ __launch_bounds__(256) void prep_vt_kernel(
    const float* __restrict__ Vg, ushort_t* __restrict__ Vt)
{
  __shared__ __align__(16) ushort_t lvt[D * QS_STRIDE];  // [d][j-in-tile], pad 72
  const int t = threadIdx.x;
  const int bh = blockIdx.x >> 4;
  const int j0 = (blockIdx.x & 15) << 6;

  {  // read 64j x 64d fp32, convert, scatter into lvt[d][j]
    const int j = t >> 2, sd = (t & 3) << 4;
    const float* src = Vg + ((size_t)bh * S + j0 + j) * D + sd;
#pragma unroll
    for (int c = 0; c < 4; ++c) {
      float4 f = *(const float4*)(src + (c << 2));
      lvt[(sd + (c << 2) + 0) * QS_STRIDE + j] = f2b(f.x);
      lvt[(sd + (c << 2) + 1) * QS_STRIDE + j] = f2b(f.y);
      lvt[(sd + (c << 2) + 2) * QS_STRIDE + j] = f2b(f.z);
      lvt[(sd + (c << 2) + 3) * QS_STRIDE + j] = f2b(f.w);
    }
  }
  __syncthreads();
  {  // write rows of Vt coalesced
    const int d = t >> 2, sj = (t & 3) << 4;
    ushort_t tmp[16];
#pragma unroll
    for (int c = 0; c < 4; ++c)
      *(ushort4*)&tmp[c << 2] = *(const ushort4*)&lvt[d * QS_STRIDE + sj + (c << 2)];
    ushort_t* dst = Vt + ((size_t)bh * D + d) * S + j0 + sj;
    *(uint4*)dst = *(const uint4*)&tmp[0];
    *(uint4*)(dst + 8) = *(const uint4*)&tmp[8];
  }
}

__global__ __launch_bounds__(512, 4) void attn_kernel(
    const float* __restrict__ Qg, const ushort_t* __restrict__ Kb,
    const ushort_t* __restrict__ Vtb, const int* __restrict__ PADg,
    float* __restrict__ OCTX, float* __restrict__ OW)
{
  __shared__ __align__(16) ushort_t wb[TQ * WB_STRIDE];   // 33536 B  scores/weights
  __shared__ __align__(16) ushort_t ub[KT * KB_STRIDE];   // 36864 B  K-tile / Vt-tile / pbuf
  __shared__ __align__(16) ushort_t qs[TQ * QS_STRIDE];   //  2304 B
  __shared__ __align__(16) float pbias[S];                //  4096 B

  const int t  = threadIdx.x;
  const int w  = t >> 6;
  const int l  = t & 63;
  const int la = l & 15;
  const int lb = l >> 4;
  const int blk = blockIdx.x;
  const int bh  = blk >> 6;     // 64 consecutive blocks share one head (L2 reuse)
  const int qt  = blk & 63;
  const int qr0 = qt << 4;

  const size_t head = (size_t)bh * S * D;

  // ---- Phase 0: stage Q tile (bf16) + pad bias ----
  if (t < 256) {
    const int r = t >> 4, c4 = (t & 15) << 2;
    const float4 qv = *(const float4*)(Qg + head + (size_t)(qr0 + r) * D + c4);
    ushort4 o; o.x = f2b(qv.x); o.y = f2b(qv.y); o.z = f2b(qv.z); o.w = f2b(qv.w);
    *(ushort4*)&qs[r * QS_STRIDE + c4] = o;
  } else {
    const int* pp = PADg + (size_t)(bh >> 4) * S;   // b = bh / H
    for (int j = t - 256; j < S; j += 256) pbias[j] = pp[j] ? NEG : 0.0f;
  }
  __syncthreads();

  // Persistent Q A-frags: A[m=la][k=lb*8+j], k-halves of D=64
  const bf16x8 aq0 = *(const bf16x8*)&qs[la * QS_STRIDE +  0 + (lb << 3)];
  const bf16x8 aq1 = *(const bf16x8*)&qs[la * QS_STRIDE + 32 + (lb << 3)];

  // ---- Phase 1: QK^T -> raw bf16 scores in wb ----
  for (int kt = 0; kt < NKT; ++kt) {
    {  // copy 256x64 bf16 K rows -> padded LDS (pure uint4 copy)
      const ushort_t* kp = Kb + head + (size_t)(kt * KT) * D;
      const int row = t >> 1, half = (t & 1) << 5;
      const ushort_t* src = kp + row * D + half;
      ushort_t* dst = &ub[row * KB_STRIDE + half];
#pragma unroll
      for (int i = 0; i < 4; ++i)
        *(uint4*)(dst + (i << 3)) = *(const uint4*)(src + (i << 3));
    }
    __syncthreads();
#pragma unroll
    for (int sj = 0; sj < 2; ++sj) {          // wave owns 32 keys -> 2 subtiles of 16
      const int j0 = (w << 5) + (sj << 4);
      f32x4 acc = {0.f, 0.f, 0.f, 0.f};
      bf16x8 b0 = *(const bf16x8*)&ub[(j0 + la) * KB_STRIDE +  0 + (lb << 3)];
      acc = __builtin_amdgcn_mfma_f32_16x16x32_bf16(aq0, b0, acc, 0, 0, 0);
      bf16x8 b1 = *(const bf16x8*)&ub[(j0 + la) * KB_STRIDE + 32 + (lb << 3)];
      acc = __builtin_amdgcn_mfma_f32_16x16x32_bf16(aq1, b1, acc, 0, 0, 0);
#pragma unroll
      for (int i = 0; i < 4; ++i)             // D: row=(lb*4+i)=q, col=la=key
        wb[((lb << 2) + i) * WB_STRIDE + kt * KT + j0 + la] = f2b(acc[i]);
    }
    __syncthreads();
  }

  // ---- Phase 2: fp32 softmax (2 rows per wave), in-place wb + global weights ----
#pragma unroll
  for (int rr = 0; rr < 2; ++rr) {
    const int r  = (w << 1) + rr;
    const int qr = qr0 + r;
    float lg[16];
    float m = -3.0e38f;
#pragma unroll
    for (int ii = 0; ii < 8; ++ii) {
      const int j = (l << 1) + (ii << 7);
      uint32_t pr = *(const uint32_t*)&wb[r * WB_STRIDE + j];
      float2 pb = *(const float2*)&pbias[j];
      float l0 = b2f(pr & 0xffffu) * SCALE + pb.x + ((j     > qr) ? NEG : 0.0f);
      float l1 = b2f(pr >> 16)     * SCALE + pb.y + ((j + 1 > qr) ? NEG : 0.0f);
      lg[2 * ii] = l0; lg[2 * ii + 1] = l1;
      m = fmaxf(m, fmaxf(l0, l1));
    }
#pragma unroll
    for (int off = 32; off > 0; off >>= 1) m = fmaxf(m, __shfl_xor(m, off, 64));
    float sum = 0.f;
#pragma unroll
    for (int x = 0; x < 16; ++x) { lg[x] = __expf(lg[x] - m); sum += lg[x]; }
#pragma unroll
    for (int off = 32; off > 0; off >>= 1) sum += __shfl_xor(sum, off, 64);
    const float inv = 1.0f / sum;
    float* orow = OW + (size_t)(bh * S + qr) * S;
#pragma unroll
    for (int ii = 0; ii < 8; ++ii) {
      const int j = (l << 1) + (ii << 7);
      float w0 = lg[2 * ii] * inv, w1 = lg[2 * ii + 1] * inv;
      *(uint32_t*)&wb[r * WB_STRIDE + j] = ((uint32_t)f2b(w1) << 16) | (uint32_t)f2b(w0);
      *(float2*)&orow[j] = make_float2(w0, w1);
    }
  }
  __syncthreads();

  // ---- Phase 3: PV. wave -> (d-tile = (w&3)*16, j-half = w>>2) ----
  const int jh = w >> 2;
  const int d0 = (w & 3) << 4;
  f32x4 cacc = {0.f, 0.f, 0.f, 0.f};
  for (int kt = 0; kt < NKT; ++kt) {
    {  // copy 64d x 256j bf16 Vt rows -> padded LDS (pure uint4 copy)
      const ushort_t* vp = Vtb + (size_t)bh * D * S + kt * KT;
      const int dd = t >> 3, seg = (t & 7) << 5;
      const ushort_t* src = vp + (size_t)dd * S + seg;
      ushort_t* dst = &ub[dd * VT_STRIDE + seg];
#pragma unroll
      for (int i = 0; i < 4; ++i)
        *(uint4*)(dst + (i << 3)) = *(const uint4*)(src + (i << 3));
    }
    __syncthreads();
#pragma unroll
    for (int ks = 0; ks < 4; ++ks) {
      const int jt = jh * 128 + ks * 32;
      bf16x8 af = *(const bf16x8*)&wb[la * WB_STRIDE + kt * KT + jt + (lb << 3)];
      bf16x8 bf = *(const bf16x8*)&ub[(d0 + la) * VT_STRIDE + jt + (lb << 3)];
      cacc = __builtin_amdgcn_mfma_f32_16x16x32_bf16(af, bf, cacc, 0, 0, 0);
    }
    __syncthreads();
  }

  // ---- Phase 4: reduce the two j-halves, store context ----
  float* pbuf = (float*)ub;                    // 4*16*20 fp32, padded
  if (w >= 4) {
#pragma unroll
    for (int i = 0; i < 4; ++i)
      pbuf[(w - 4) * 320 + ((lb << 2) + i) * 20 + la] = cacc[i];
  }
  __syncthreads();
  if (w < 4) {
#pragma unroll
    for (int i = 0; i < 4; ++i) {
      const int qrow = (lb << 2) + i;
      OCTX[((size_t)(bh * S) + qr0 + qrow) * D + d0 + la] =
          cacc[i] + pbuf[w * 320 + qrow * 20 + la];
    }
  }
}

extern "C" void kernel_launch(void* const* d_in, const int* in_sizes, int n_in,
                              void* d_out, int out_size, void* d_ws, size_t ws_size,
                              hipStream_t stream) {
  const float* q   = (const float*)d_in[0];
  const float* k   = (const float*)d_in[1];
  const float* v   = (const float*)d_in[2];
  const int*   pad = (const int*)d_in[3];
  // d_in[4] (look_ahead_mask) is reproduced analytically from indices.
  float* ctx  = (float*)d_out;
  float* wout = (float*)d_out + (size_t)4 * 16 * S * D;   // weights after context

  ushort_t* Kb  = (ushort_t*)d_ws;                          // 8 MB bf16 K
  ushort_t* Vtb = (ushort_t*)d_ws + (size_t)4 * 16 * S * D; // 8 MB bf16 V^T

  prep_k_kernel <<<dim3(2048), dim3(256), 0, stream>>>(k, Kb);
  prep_vt_kernel<<<dim3(1024), dim3(256), 0, stream>>>(v, Vtb);
  attn_kernel   <<<dim3(4096), dim3(512), 0, stream>>>(q, Kb, Vtb, pad, ctx, wout);
}

// Round 3
// 409.693 us; speedup vs baseline: 1.3104x; 1.0104x over previous
//
#include <hip/hip_runtime.h>
#include <stdint.h>

#define S 1024
#define D 64
#define TQ 16
#define KT 128
#define NKT 8
#define NEG (-1e15f)
#define SCALE 0.125f

#define WB_STRIDE 1048   // bf16 elems; 2096 B row, 16B-aligned
#define KB_STRIDE 72     // bf16 elems; 144 B row (16B mult)
#define VT_STRIDE 136    // bf16 elems; 272 B row (16B mult)
#define QS_STRIDE 72

typedef __bf16 bf16x8 __attribute__((ext_vector_type(8)));
typedef float f32x4 __attribute__((ext_vector_type(4)));
typedef unsigned short ushort_t;

__device__ __forceinline__ unsigned short f2b(float f) {
  union { float f; uint32_t u; } c; c.f = f;
  uint32_t u = c.u;
  return (unsigned short)((u + 0x7fffu + ((u >> 16) & 1u)) >> 16);  // RNE
}
__device__ __forceinline__ float b2f(uint32_t u) {
  union { uint32_t u; float f; } c; c.u = u << 16;
  return c.f;
}

// ---- prep 1: K fp32 -> bf16, straight layout [bh][j][d] ----
__global__ __launch_bounds__(256) void prep_k_kernel(
    const float* __restrict__ Kg, ushort_t* __restrict__ Kb)
{
  const size_t idx = ((size_t)blockIdx.x * 256 + threadIdx.x) * 8;
  float4 a = *(const float4*)(Kg + idx);
  float4 b = *(const float4*)(Kg + idx + 4);
  ushort_t tmp[8];
  tmp[0]=f2b(a.x); tmp[1]=f2b(a.y); tmp[2]=f2b(a.z); tmp[3]=f2b(a.w);
  tmp[4]=f2b(b.x); tmp[5]=f2b(b.y); tmp[6]=f2b(b.z); tmp[7]=f2b(b.w);
  *(uint4*)(Kb + idx) = *(const uint4*)tmp;
}

// ---- prep 2: V fp32 [bh][j][d] -> bf16 transposed Vt [bh][d][j] ----
__global__ __launch_bounds__(256) void prep_vt_kernel(
    const float* __restrict__ Vg, ushort_t* __restrict__ Vt)
{
  __shared__ __align__(16) ushort_t lvt[D * QS_STRIDE];  // [d][j-in-tile], pad 72
  const int t = threadIdx.x;
  const int bh = blockIdx.x >> 4;
  const int j0 = (blockIdx.x & 15) << 6;

  {  // read 64j x 64d fp32, convert, scatter into lvt[d][j]
    const int j = t >> 2, sd = (t & 3) << 4;
    const float* src = Vg + ((size_t)bh * S + j0 + j) * D + sd;
#pragma unroll
    for (int c = 0; c < 4; ++c) {
      float4 f = *(const float4*)(src + (c << 2));
      lvt[(sd + (c << 2) + 0) * QS_STRIDE + j] = f2b(f.x);
      lvt[(sd + (c << 2) + 1) * QS_STRIDE + j] = f2b(f.y);
      lvt[(sd + (c << 2) + 2) * QS_STRIDE + j] = f2b(f.z);
      lvt[(sd + (c << 2) + 3) * QS_STRIDE + j] = f2b(f.w);
    }
  }
  __syncthreads();
  {  // write rows of Vt coalesced
    const int d = t >> 2, sj = (t & 3) << 4;
    ushort_t tmp[16];
#pragma unroll
    for (int c = 0; c < 4; ++c)
      *(ushort4*)&tmp[c << 2] = *(const ushort4*)&lvt[d * QS_STRIDE + sj + (c << 2)];
    ushort_t* dst = Vt + ((size_t)bh * D + d) * S + j0 + sj;
    *(uint4*)dst = *(const uint4*)&tmp[0];
    *(uint4*)(dst + 8) = *(const uint4*)&tmp[8];
  }
}

__global__ __launch_bounds__(512, 6) void attn_kernel(
    const float* __restrict__ Qg, const ushort_t* __restrict__ Kb,
    const ushort_t* __restrict__ Vtb, const int* __restrict__ PADg,
    float* __restrict__ OCTX, float* __restrict__ OW)
{
  __shared__ __align__(16) ushort_t wb[TQ * WB_STRIDE];   // 33536 B  scores/weights
  __shared__ __align__(16) ushort_t ub[KT * KB_STRIDE];   // 18432 B  K/Vt tile, pbuf

  const int t  = threadIdx.x;
  const int w  = t >> 6;
  const int l  = t & 63;
  const int la = l & 15;
  const int lb = l >> 4;
  const int blk = blockIdx.x;
  const int bh  = blk >> 6;     // 64 consecutive blocks share one head (L2 reuse)
  const int qt  = blk & 63;
  const int qr0 = qt << 4;

  const size_t head = (size_t)bh * S * D;
  const int* pp = PADg + (size_t)(bh >> 4) * S;   // b = bh / H

  // ---- Q A-frags direct from global: A[m=la][k=lb*8+j], two k-halves of D=64
  bf16x8 aq0, aq1;
  {
    const float* qrow = Qg + head + (size_t)(qr0 + la) * D + (lb << 3);
    float4 q00 = *(const float4*)(qrow);
    float4 q01 = *(const float4*)(qrow + 4);
    float4 q10 = *(const float4*)(qrow + 32);
    float4 q11 = *(const float4*)(qrow + 36);
    ushort_t a0[8], a1[8];
    a0[0]=f2b(q00.x); a0[1]=f2b(q00.y); a0[2]=f2b(q00.z); a0[3]=f2b(q00.w);
    a0[4]=f2b(q01.x); a0[5]=f2b(q01.y); a0[6]=f2b(q01.z); a0[7]=f2b(q01.w);
    a1[0]=f2b(q10.x); a1[1]=f2b(q10.y); a1[2]=f2b(q10.z); a1[3]=f2b(q10.w);
    a1[4]=f2b(q11.x); a1[5]=f2b(q11.y); a1[6]=f2b(q11.z); a1[7]=f2b(q11.w);
    aq0 = *(const bf16x8*)a0;
    aq1 = *(const bf16x8*)a1;
  }

  // ---- Phase 1: QK^T -> raw bf16 scores in wb (8 tiles of 128 keys) ----
  for (int kt = 0; kt < NKT; ++kt) {
    {  // stage 128 rows x 64 cols bf16 K (32 B per thread, pure copy)
      const ushort_t* kp = Kb + head + (size_t)(kt * KT) * D;
      const int row = t >> 2, off = (t & 3) << 4;
      const ushort_t* src = kp + row * D + off;
      ushort_t* dst = &ub[row * KB_STRIDE + off];
      *(uint4*)dst = *(const uint4*)src;
      *(uint4*)(dst + 8) = *(const uint4*)(src + 8);
    }
    __syncthreads();
    {  // wave owns one 16-key subtile
      const int j0 = w << 4;
      f32x4 acc = {0.f, 0.f, 0.f, 0.f};
      bf16x8 b0 = *(const bf16x8*)&ub[(j0 + la) * KB_STRIDE + (lb << 3)];
      acc = __builtin_amdgcn_mfma_f32_16x16x32_bf16(aq0, b0, acc, 0, 0, 0);
      bf16x8 b1 = *(const bf16x8*)&ub[(j0 + la) * KB_STRIDE + 32 + (lb << 3)];
      acc = __builtin_amdgcn_mfma_f32_16x16x32_bf16(aq1, b1, acc, 0, 0, 0);
#pragma unroll
      for (int i = 0; i < 4; ++i)             // D: row=(lb*4+i)=q, col=la=key
        wb[((lb << 2) + i) * WB_STRIDE + kt * KT + j0 + la] = f2b(acc[i]);
    }
    __syncthreads();
  }

  // ---- Phase 2: fp32 softmax (2 rows per wave), in-place wb + global weights ----
#pragma unroll
  for (int rr = 0; rr < 2; ++rr) {
    const int r  = (w << 1) + rr;
    const int qr = qr0 + r;
    float lg[16];
    float m = -3.0e38f;
#pragma unroll
    for (int ii = 0; ii < 8; ++ii) {
      const int j = (l << 1) + (ii << 7);
      uint32_t pr = *(const uint32_t*)&wb[r * WB_STRIDE + j];
      int2 pv = *(const int2*)&pp[j];
      float l0 = b2f(pr & 0xffffu) * SCALE + (pv.x ? NEG : 0.0f) + ((j     > qr) ? NEG : 0.0f);
      float l1 = b2f(pr >> 16)     * SCALE + (pv.y ? NEG : 0.0f) + ((j + 1 > qr) ? NEG : 0.0f);
      lg[2 * ii] = l0; lg[2 * ii + 1] = l1;
      m = fmaxf(m, fmaxf(l0, l1));
    }
#pragma unroll
    for (int off = 32; off > 0; off >>= 1) m = fmaxf(m, __shfl_xor(m, off, 64));
    float sum = 0.f;
#pragma unroll
    for (int x = 0; x < 16; ++x) { lg[x] = __expf(lg[x] - m); sum += lg[x]; }
#pragma unroll
    for (int off = 32; off > 0; off >>= 1) sum += __shfl_xor(sum, off, 64);
    const float inv = 1.0f / sum;
    float* orow = OW + (size_t)(bh * S + qr) * S;
#pragma unroll
    for (int ii = 0; ii < 8; ++ii) {
      const int j = (l << 1) + (ii << 7);
      float w0 = lg[2 * ii] * inv, w1 = lg[2 * ii + 1] * inv;
      *(uint32_t*)&wb[r * WB_STRIDE + j] = ((uint32_t)f2b(w1) << 16) | (uint32_t)f2b(w0);
      *(float2*)&orow[j] = make_float2(w0, w1);
    }
  }
  __syncthreads();

  // ---- Phase 3: PV. wave -> (d-tile = (w&3)*16, j-half = w>>2) ----
  const int jh = w >> 2;
  const int d0 = (w & 3) << 4;
  f32x4 cacc = {0.f, 0.f, 0.f, 0.f};
  for (int kt = 0; kt < NKT; ++kt) {
    {  // stage 64d x 128j bf16 Vt tile (32 B per thread, pure copy)
      const ushort_t* vp = Vtb + (size_t)bh * D * S + kt * KT;
      const int dd = t >> 3, off = (t & 7) << 4;
      const ushort_t* src = vp + (size_t)dd * S + off;
      ushort_t* dst = &ub[dd * VT_STRIDE + off];
      *(uint4*)dst = *(const uint4*)src;
      *(uint4*)(dst + 8) = *(const uint4*)(src + 8);
    }
    __syncthreads();
#pragma unroll
    for (int ks = 0; ks < 2; ++ks) {
      const int jt = jh * 64 + ks * 32;
      bf16x8 af = *(const bf16x8*)&wb[la * WB_STRIDE + kt * KT + jt + (lb << 3)];
      bf16x8 bf = *(const bf16x8*)&ub[(d0 + la) * VT_STRIDE + jt + (lb << 3)];
      cacc = __builtin_amdgcn_mfma_f32_16x16x32_bf16(af, bf, cacc, 0, 0, 0);
    }
    __syncthreads();
  }

  // ---- Phase 4: reduce the two j-halves, store context ----
  float* pbuf = (float*)ub;                    // 4*16*20 fp32, padded (5120 B)
  if (w >= 4) {
#pragma unroll
    for (int i = 0; i < 4; ++i)
      pbuf[(w - 4) * 320 + ((lb << 2) + i) * 20 + la] = cacc[i];
  }
  __syncthreads();
  if (w < 4) {
#pragma unroll
    for (int i = 0; i < 4; ++i) {
      const int qrow = (lb << 2) + i;
      OCTX[((size_t)(bh * S) + qr0 + qrow) * D + d0 + la] =
          cacc[i] + pbuf[w * 320 + qrow * 20 + la];
    }
  }
}

extern "C" void kernel_launch(void* const* d_in, const int* in_sizes, int n_in,
                              void* d_out, int out_size, void* d_ws, size_t ws_size,
                              hipStream_t stream) {
  const float* q   = (const float*)d_in[0];
  const float* k   = (const float*)d_in[1];
  const float* v   = (const float*)d_in[2];
  const int*   pad = (const int*)d_in[3];
  // d_in[4] (look_ahead_mask) is reproduced analytically from indices.
  float* ctx  = (float*)d_out;
  float* wout = (float*)d_out + (size_t)4 * 16 * S * D;   // weights after context

  ushort_t* Kb  = (ushort_t*)d_ws;                          // 8 MB bf16 K
  ushort_t* Vtb = (ushort_t*)d_ws + (size_t)4 * 16 * S * D; // 8 MB bf16 V^T

  prep_k_kernel <<<dim3(2048), dim3(256), 0, stream>>>(k, Kb);
  prep_vt_kernel<<<dim3(1024), dim3(256), 0, stream>>>(v, Vtb);
  attn_kernel   <<<dim3(4096), dim3(512), 0, stream>>>(q, Kb, Vtb, pad, ctx, wout);
}